// Round 1
// baseline (1811.595 us; speedup 1.0000x reference)
//
#include <hip/hip_runtime.h>
#include <cstdint>
#include <cstddef>

// BloomAttention MI355X implementation.
// Pipeline: cvt(hidden->bf16) ; cvt+transpose(Wqkv) -> GEMM1(bf16, m97-style)
//           -> fused[B,S,H,3,HD] bf16 ; transpose V -> VT[B,H,HD,S]
//           -> flash attention (online softmax, MFMA 16x16x32)
//           -> ctx[B,S,H*HD] bf16 ; cvt+transpose(Wd) -> GEMM2 + bias + residual -> f32 out.
// Workspace layout (256 MB total, with liveness overlap):
//   [0,32M)    A_bf16   (later reused as ctx)
//   [32,128M)  W1T      (later reused as W2T)
//   [128,224M) fused
//   [224,256M) VT

typedef unsigned short u16;
typedef unsigned int u32;
typedef __bf16 bf16x8 __attribute__((ext_vector_type(8)));
typedef float f32x4 __attribute__((ext_vector_type(4)));
typedef u16 u16x4 __attribute__((ext_vector_type(4)));

#define LDS_AS(p) ((__attribute__((address_space(3))) u32*)(p))
#define GLB_AS(p) ((__attribute__((address_space(1))) u32*)(p))

// async global->LDS, 16B per lane; LDS dest = wave-uniform base + lane*16
__device__ __forceinline__ void load16(const void* g, void* l) {
  __builtin_amdgcn_global_load_lds(GLB_AS(g), LDS_AS(l), 16, 0, 0);
}

__device__ __forceinline__ u16 f2bf(float f) {
  union { float f; u32 u; } x; x.f = f;
  u32 r = x.u + 0x7fffu + ((x.u >> 16) & 1u);  // RNE
  return (u16)(r >> 16);
}

// ---------------- elementwise f32 -> bf16 ----------------
__global__ __launch_bounds__(256) void cvt_bf16(const float* __restrict__ in,
                                                u16* __restrict__ out, int n) {
  int i = (blockIdx.x * 256 + threadIdx.x) * 4;
  if (i >= n) return;
  float4 v = *(const float4*)(in + i);
  u16x4 o = { f2bf(v.x), f2bf(v.y), f2bf(v.z), f2bf(v.w) };
  *(u16x4*)(out + i) = o;
}

// ---------------- f32 [K][N] -> bf16 [N][K] (transpose+convert) ----------------
__global__ __launch_bounds__(256) void cvt_transpose(const float* __restrict__ W,
                                                     u16* __restrict__ WT,
                                                     int K, int N) {
  __shared__ float tile[32][33];
  int n0 = blockIdx.x * 32, k0 = blockIdx.y * 32;
  int tx = threadIdx.x & 31, ty = threadIdx.x >> 5;  // 32 x 8
  for (int r = ty; r < 32; r += 8)
    tile[r][tx] = W[(size_t)(k0 + r) * N + n0 + tx];
  __syncthreads();
  for (int r = ty; r < 32; r += 8)
    WT[(size_t)(n0 + r) * K + k0 + tx] = f2bf(tile[tx][r]);
}

// ---------------- V slice of fused -> VT[B*H][HD][S] ----------------
__global__ __launch_bounds__(256) void transpose_v(const u16* __restrict__ fused,
                                                   u16* __restrict__ vt) {
  __shared__ __align__(16) u16 tile[64][136];
  int st = blockIdx.x * 64, bh = blockIdx.y;
  int b = bh >> 5, h = bh & 31;
  int tx = threadIdx.x & 15, ty = threadIdx.x >> 4;  // 16 x 16
  for (int r = ty; r < 64; r += 16) {
    const u16* src = fused + (size_t)(b * 2048 + st + r) * 12288 + h * 384 + 256 + tx * 8;
    u16x4 a = *(const u16x4*)(src);
    u16x4 c = *(const u16x4*)(src + 4);
    *(u16x4*)&tile[r][tx * 8] = a;
    *(u16x4*)&tile[r][tx * 8 + 4] = c;
  }
  __syncthreads();
  for (int d = ty; d < 128; d += 16) {
    u16x4 o = { tile[tx * 4 + 0][d], tile[tx * 4 + 1][d],
                tile[tx * 4 + 2][d], tile[tx * 4 + 3][d] };
    *(u16x4*)(vt + ((size_t)bh * 128 + d) * 2048 + st + tx * 4) = o;
  }
}

// ---------------- m97-style bf16 GEMM: C = A[M,K] * BT[N,K]^T + bias (+res) ----------------
// EPI 0: out bf16.  EPI 1: out f32 with +residual.
template <int EPI>
__global__ __launch_bounds__(256) void gemm_bt(const u16* __restrict__ A,
                                               const u16* __restrict__ BT,
                                               const float* __restrict__ bias,
                                               const float* __restrict__ res,
                                               void* __restrict__ out,
                                               int M, int N, int K) {
  __shared__ __align__(16) u16 As[128 * 32];
  __shared__ __align__(16) u16 Bs[128 * 32];
  const int tid = threadIdx.x, wave = tid >> 6, lane = tid & 63;
  const int quad = lane >> 4, l16 = lane & 15;
  const int m0 = blockIdx.y * 128, n0 = blockIdx.x * 128;
  const int wm = (wave >> 1) * 64, wn = (wave & 1) * 64;

  const f32x4 fz = {0.f, 0.f, 0.f, 0.f};
  f32x4 acc[4][4];
  for (int i = 0; i < 4; ++i)
    for (int j = 0; j < 4; ++j) acc[i][j] = fz;

  // staging geometry: tile 128x32 bf16 = 8 KB, 8 wave-instrs, 2 per wave
  const int i0 = wave * 2;
  const int t0 = i0 * 1024 + lane * 16;
  const int t1 = t0 + 1024;
  const int rA0 = t0 >> 6, cA0 = t0 & 63;
  const int rA1 = t1 >> 6, cA1 = t1 & 63;

  for (int k0 = 0; k0 < K; k0 += 32) {
    __syncthreads();  // previous iter's readers done
    load16((const char*)(A + (size_t)(m0 + rA0) * K + k0) + cA0, (char*)As + i0 * 1024);
    load16((const char*)(A + (size_t)(m0 + rA1) * K + k0) + cA1, (char*)As + i0 * 1024 + 1024);
    load16((const char*)(BT + (size_t)(n0 + rA0) * K + k0) + cA0, (char*)Bs + i0 * 1024);
    load16((const char*)(BT + (size_t)(n0 + rA1) * K + k0) + cA1, (char*)Bs + i0 * 1024 + 1024);
    __syncthreads();  // drains vmcnt

    bf16x8 af[4], bfv[4];
    for (int i = 0; i < 4; ++i)
      af[i] = *(const bf16x8*)((const char*)As + ((wm + i * 16 + l16) * 32 + quad * 8) * 2);
    for (int j = 0; j < 4; ++j)
      bfv[j] = *(const bf16x8*)((const char*)Bs + ((wn + j * 16 + l16) * 32 + quad * 8) * 2);
    for (int i = 0; i < 4; ++i)
      for (int j = 0; j < 4; ++j)
        acc[i][j] = __builtin_amdgcn_mfma_f32_16x16x32_bf16(af[i], bfv[j], acc[i][j], 0, 0, 0);
  }

  // epilogue: C/D layout col=lane&15, row=quad*4+t
  for (int i = 0; i < 4; ++i) {
    int row = m0 + wm + i * 16 + quad * 4;
    for (int j = 0; j < 4; ++j) {
      int col = n0 + wn + j * 16 + l16;
      float bv = bias[col];
      for (int t = 0; t < 4; ++t) {
        float v = acc[i][j][t] + bv;
        size_t idx = (size_t)(row + t) * N + col;
        if (EPI == 1) {
          ((float*)out)[idx] = v + res[idx];
        } else {
          ((u16*)out)[idx] = f2bf(v);
        }
      }
    }
  }
}

// ---------------- flash attention ----------------
// grid (S/64, B*H), block 256 (4 waves). Wave w owns q rows [q0+w*16, +16).
__global__ __launch_bounds__(256) void flash_attn(const u16* __restrict__ fused,
                                                  const u16* __restrict__ vt,
                                                  const float* __restrict__ alibi,
                                                  u16* __restrict__ ctx) {
  __shared__ __align__(16) u16 Qs[64 * 128];
  __shared__ __align__(16) u16 Ks[64 * 128];
  __shared__ __align__(16) u16 VTs[128 * 64];
  __shared__ __align__(16) u16 Ps[64 * 64];

  const int tid = threadIdx.x, wave = tid >> 6, lane = tid & 63;
  const int quad = lane >> 4, l16 = lane & 15;
  const int qt = blockIdx.x, bh = blockIdx.y;
  const int b = bh >> 5, h = bh & 31;
  const int q0 = qt * 64;
  const float scale = 0.08838834764831845f;  // 1/sqrt(128)
  const f32x4 fz = {0.f, 0.f, 0.f, 0.f};

  // stage Q tile [64 q][128 d] (bf16, 16 KB): 16 wave-instrs, 4 per wave
  for (int j = 0; j < 4; ++j) {
    int inst = wave * 4 + j;
    int t = inst * 1024 + lane * 16;
    int row = t >> 8, colb = t & 255;
    load16((const char*)(fused + (size_t)(b * 2048 + q0 + row) * 12288 + h * 384) + colb,
           (char*)Qs + inst * 1024);
  }

  float m_st[4] = {-__builtin_inff(), -__builtin_inff(), -__builtin_inff(), -__builtin_inff()};
  float l_st[4] = {0.f, 0.f, 0.f, 0.f};
  f32x4 o_acc[8];
  for (int f = 0; f < 8; ++f) o_acc[f] = fz;

  const int nkv = qt + 1;  // causal: only kv tiles <= q tile
  for (int kvt = 0; kvt < nkv; ++kvt) {
    const int kv0 = kvt * 64;
    __syncthreads();  // previous iter readers of Ks/VTs done
    for (int j = 0; j < 4; ++j) {  // K tile [64 kv][128 d]
      int inst = wave * 4 + j;
      int t = inst * 1024 + lane * 16;
      int row = t >> 8, colb = t & 255;
      load16((const char*)(fused + (size_t)(b * 2048 + kv0 + row) * 12288 + h * 384 + 128) + colb,
             (char*)Ks + inst * 1024);
    }
    for (int j = 0; j < 4; ++j) {  // VT tile [128 d][64 kv]
      int inst = wave * 4 + j;
      int t = inst * 1024 + lane * 16;
      int row = t >> 7, colb = t & 127;
      load16((const char*)(vt + ((size_t)bh * 128 + row) * 2048 + kv0) + colb,
             (char*)VTs + inst * 1024);
    }
    __syncthreads();  // drains vmcnt (Q included on first iter)

    // S = Q K^T : per wave 16q x 64kv
    f32x4 sa[4];
    for (int j = 0; j < 4; ++j) sa[j] = fz;
    for (int kk = 0; kk < 4; ++kk) {
      bf16x8 a = *(const bf16x8*)((const char*)Qs + ((wave * 16 + l16) * 128 + kk * 32 + quad * 8) * 2);
      for (int j = 0; j < 4; ++j) {
        bf16x8 bv = *(const bf16x8*)((const char*)Ks + ((j * 16 + l16) * 128 + kk * 32 + quad * 8) * 2);
        sa[j] = __builtin_amdgcn_mfma_f32_16x16x32_bf16(a, bv, sa[j], 0, 0, 0);
      }
    }

    // scale + alibi + causal mask
    float al[4];
    for (int j = 0; j < 4; ++j) al[j] = alibi[(size_t)bh * 2048 + kv0 + j * 16 + l16];
    float p[4][4];
    const bool diag = (kvt == qt);
    for (int j = 0; j < 4; ++j) {
      int kvg = kv0 + j * 16 + l16;
      for (int t = 0; t < 4; ++t) {
        float v = sa[j][t] * scale + al[j];
        if (diag) {
          int qg = q0 + wave * 16 + quad * 4 + t;
          if (kvg > qg) v = -__builtin_inff();
        }
        p[j][t] = v;
      }
    }

    // online softmax (row r = quad*4+t lives in 16 lanes sharing quad)
    float mnew[4], alpha[4];
    for (int t = 0; t < 4; ++t) {
      float mx = fmaxf(fmaxf(p[0][t], p[1][t]), fmaxf(p[2][t], p[3][t]));
      for (int off = 1; off < 16; off <<= 1) mx = fmaxf(mx, __shfl_xor(mx, off, 64));
      mnew[t] = fmaxf(m_st[t], mx);
      alpha[t] = __expf(m_st[t] - mnew[t]);
      m_st[t] = mnew[t];
      float rs = 0.f;
      for (int j = 0; j < 4; ++j) {
        p[j][t] = __expf(p[j][t] - mnew[t]);
        rs += p[j][t];
      }
      for (int off = 1; off < 16; off <<= 1) rs += __shfl_xor(rs, off, 64);
      l_st[t] = l_st[t] * alpha[t] + rs;
    }
    for (int f = 0; f < 8; ++f)
      for (int t = 0; t < 4; ++t) o_acc[f][t] *= alpha[t];

    // P round-trip through LDS: C-layout -> A-layout (wave-private rows)
    for (int j = 0; j < 4; ++j)
      for (int t = 0; t < 4; ++t)
        Ps[(wave * 16 + quad * 4 + t) * 64 + j * 16 + l16] = f2bf(p[j][t]);

    // O += P V  (A from Ps, B from VTs = V^T rows, k-contiguous)
    for (int kk = 0; kk < 2; ++kk) {
      bf16x8 a = *(const bf16x8*)((const char*)Ps + ((wave * 16 + l16) * 64 + kk * 32 + quad * 8) * 2);
      for (int f = 0; f < 8; ++f) {
        bf16x8 bv = *(const bf16x8*)((const char*)VTs + ((f * 16 + l16) * 64 + kk * 32 + quad * 8) * 2);
        o_acc[f] = __builtin_amdgcn_mfma_f32_16x16x32_bf16(a, bv, o_acc[f], 0, 0, 0);
      }
    }
  }

  // epilogue: ctx[b,s,h*128+d] bf16
  float invl[4];
  for (int t = 0; t < 4; ++t) invl[t] = 1.0f / l_st[t];
  for (int f = 0; f < 8; ++f) {
    int d = h * 128 + f * 16 + l16;
    for (int t = 0; t < 4; ++t) {
      int row = b * 2048 + q0 + wave * 16 + quad * 4 + t;
      ctx[(size_t)row * 4096 + d] = f2bf(o_acc[f][t] * invl[t]);
    }
  }
}

// ---------------- launch ----------------
extern "C" void kernel_launch(void* const* d_in, const int* in_sizes, int n_in,
                              void* d_out, int out_size, void* d_ws, size_t ws_size,
                              hipStream_t stream) {
  const float* hs    = (const float*)d_in[0];
  const float* resid = (const float*)d_in[1];
  const float* alibi = (const float*)d_in[2];
  // d_in[3] = attention_mask: deterministic causal, computed analytically
  const float* Wqkv  = (const float*)d_in[4];
  const float* bqkv  = (const float*)d_in[5];
  const float* Wd    = (const float*)d_in[6];
  const float* bd    = (const float*)d_in[7];

  char* ws = (char*)d_ws;
  u16* Abf   = (u16*)(ws);                        // 32 MB
  u16* W1T   = (u16*)(ws + (size_t)33554432);     // 96 MB
  u16* fused = (u16*)(ws + (size_t)134217728);    // 96 MB
  u16* vtb   = (u16*)(ws + (size_t)234881024);    // 32 MB
  u16* ctx   = (u16*)(ws);                        // reuse Abf (dead after GEMM1)
  u16* W2T   = (u16*)(ws + (size_t)33554432);     // reuse W1T (dead after GEMM1)

  cvt_bf16<<<16384, 256, 0, stream>>>(hs, Abf, 16777216);
  cvt_transpose<<<dim3(384, 128), 256, 0, stream>>>(Wqkv, W1T, 4096, 12288);
  gemm_bt<0><<<dim3(96, 32), 256, 0, stream>>>(Abf, W1T, bqkv, nullptr, fused, 4096, 12288, 4096);
  transpose_v<<<dim3(32, 64), 256, 0, stream>>>(fused, vtb);
  cvt_transpose<<<dim3(128, 128), 256, 0, stream>>>(Wd, W2T, 4096, 4096);  // after GEMM1 read of W1T
  flash_attn<<<dim3(32, 64), 256, 0, stream>>>(fused, vtb, alibi, ctx);    // ctx overwrites Abf after GEMM1
  gemm_bt<1><<<dim3(32, 32), 256, 0, stream>>>(ctx, W2T, bd, resid, d_out, 4096, 4096, 4096);
}

// Round 2
// 1519.873 us; speedup vs baseline: 1.1919x; 1.1919x over previous
//
#include <hip/hip_runtime.h>
#include <cstdint>
#include <cstddef>

// BloomAttention MI355X implementation.
// Round 2: flash_attn rewritten — XOR-swizzled LDS (kills 16-way bank conflicts),
// Q fragments in registers, software-pipelined K prefetch (double-buffered K),
// V staged at iter top so both barriers drain loads that had a full compute
// phase in flight. GEMMs/transposes unchanged from round 1.
//
// Workspace layout (256 MB, liveness overlap):
//   [0,32M)    A_bf16   (later reused as ctx)
//   [32,128M)  W1T      (later reused as W2T)
//   [128,224M) fused
//   [224,256M) VT

typedef unsigned short u16;
typedef unsigned int u32;
typedef __bf16 bf16x8 __attribute__((ext_vector_type(8)));
typedef float f32x4 __attribute__((ext_vector_type(4)));
typedef u16 u16x4 __attribute__((ext_vector_type(4)));

#define LDS_AS(p) ((__attribute__((address_space(3))) u32*)(p))
#define GLB_AS(p) ((__attribute__((address_space(1))) u32*)(p))

// async global->LDS, 16B per lane; LDS dest = wave-uniform base + lane*16,
// global source is PER-LANE (this is what makes the XOR swizzle possible).
__device__ __forceinline__ void load16(const void* g, void* l) {
  __builtin_amdgcn_global_load_lds(GLB_AS(g), LDS_AS(l), 16, 0, 0);
}

__device__ __forceinline__ u16 f2bf(float f) {
  union { float f; u32 u; } x; x.f = f;
  u32 r = x.u + 0x7fffu + ((x.u >> 16) & 1u);  // RNE
  return (u16)(r >> 16);
}

// ---------------- elementwise f32 -> bf16 ----------------
__global__ __launch_bounds__(256) void cvt_bf16(const float* __restrict__ in,
                                                u16* __restrict__ out, int n) {
  int i = (blockIdx.x * 256 + threadIdx.x) * 4;
  if (i >= n) return;
  float4 v = *(const float4*)(in + i);
  u16x4 o = { f2bf(v.x), f2bf(v.y), f2bf(v.z), f2bf(v.w) };
  *(u16x4*)(out + i) = o;
}

// ---------------- f32 [K][N] -> bf16 [N][K] (transpose+convert) ----------------
__global__ __launch_bounds__(256) void cvt_transpose(const float* __restrict__ W,
                                                     u16* __restrict__ WT,
                                                     int K, int N) {
  __shared__ float tile[32][33];
  int n0 = blockIdx.x * 32, k0 = blockIdx.y * 32;
  int tx = threadIdx.x & 31, ty = threadIdx.x >> 5;  // 32 x 8
  for (int r = ty; r < 32; r += 8)
    tile[r][tx] = W[(size_t)(k0 + r) * N + n0 + tx];
  __syncthreads();
  for (int r = ty; r < 32; r += 8)
    WT[(size_t)(n0 + r) * K + k0 + tx] = f2bf(tile[tx][r]);
}

// ---------------- V slice of fused -> VT[B*H][HD][S] ----------------
__global__ __launch_bounds__(256) void transpose_v(const u16* __restrict__ fused,
                                                   u16* __restrict__ vt) {
  __shared__ __align__(16) u16 tile[64][136];
  int st = blockIdx.x * 64, bh = blockIdx.y;
  int b = bh >> 5, h = bh & 31;
  int tx = threadIdx.x & 15, ty = threadIdx.x >> 4;  // 16 x 16
  for (int r = ty; r < 64; r += 16) {
    const u16* src = fused + (size_t)(b * 2048 + st + r) * 12288 + h * 384 + 256 + tx * 8;
    u16x4 a = *(const u16x4*)(src);
    u16x4 c = *(const u16x4*)(src + 4);
    *(u16x4*)&tile[r][tx * 8] = a;
    *(u16x4*)&tile[r][tx * 8 + 4] = c;
  }
  __syncthreads();
  for (int d = ty; d < 128; d += 16) {
    u16x4 o = { tile[tx * 4 + 0][d], tile[tx * 4 + 1][d],
                tile[tx * 4 + 2][d], tile[tx * 4 + 3][d] };
    *(u16x4*)(vt + ((size_t)bh * 128 + d) * 2048 + st + tx * 4) = o;
  }
}

// ---------------- m97-style bf16 GEMM: C = A[M,K] * BT[N,K]^T + bias (+res) ----------------
// EPI 0: out bf16.  EPI 1: out f32 with +residual.
template <int EPI>
__global__ __launch_bounds__(256) void gemm_bt(const u16* __restrict__ A,
                                               const u16* __restrict__ BT,
                                               const float* __restrict__ bias,
                                               const float* __restrict__ res,
                                               void* __restrict__ out,
                                               int M, int N, int K) {
  __shared__ __align__(16) u16 As[128 * 32];
  __shared__ __align__(16) u16 Bs[128 * 32];
  const int tid = threadIdx.x, wave = tid >> 6, lane = tid & 63;
  const int quad = lane >> 4, l16 = lane & 15;
  const int m0 = blockIdx.y * 128, n0 = blockIdx.x * 128;
  const int wm = (wave >> 1) * 64, wn = (wave & 1) * 64;

  const f32x4 fz = {0.f, 0.f, 0.f, 0.f};
  f32x4 acc[4][4];
  for (int i = 0; i < 4; ++i)
    for (int j = 0; j < 4; ++j) acc[i][j] = fz;

  // staging geometry: tile 128x32 bf16 = 8 KB, 8 wave-instrs, 2 per wave
  const int i0 = wave * 2;
  const int t0 = i0 * 1024 + lane * 16;
  const int t1 = t0 + 1024;
  const int rA0 = t0 >> 6, cA0 = t0 & 63;
  const int rA1 = t1 >> 6, cA1 = t1 & 63;

  for (int k0 = 0; k0 < K; k0 += 32) {
    __syncthreads();  // previous iter's readers done
    load16((const char*)(A + (size_t)(m0 + rA0) * K + k0) + cA0, (char*)As + i0 * 1024);
    load16((const char*)(A + (size_t)(m0 + rA1) * K + k0) + cA1, (char*)As + i0 * 1024 + 1024);
    load16((const char*)(BT + (size_t)(n0 + rA0) * K + k0) + cA0, (char*)Bs + i0 * 1024);
    load16((const char*)(BT + (size_t)(n0 + rA1) * K + k0) + cA1, (char*)Bs + i0 * 1024 + 1024);
    __syncthreads();  // drains vmcnt

    bf16x8 af[4], bfv[4];
    for (int i = 0; i < 4; ++i)
      af[i] = *(const bf16x8*)((const char*)As + ((wm + i * 16 + l16) * 32 + quad * 8) * 2);
    for (int j = 0; j < 4; ++j)
      bfv[j] = *(const bf16x8*)((const char*)Bs + ((wn + j * 16 + l16) * 32 + quad * 8) * 2);
    for (int i = 0; i < 4; ++i)
      for (int j = 0; j < 4; ++j)
        acc[i][j] = __builtin_amdgcn_mfma_f32_16x16x32_bf16(af[i], bfv[j], acc[i][j], 0, 0, 0);
  }

  // epilogue: C/D layout col=lane&15, row=quad*4+t
  for (int i = 0; i < 4; ++i) {
    int row = m0 + wm + i * 16 + quad * 4;
    for (int j = 0; j < 4; ++j) {
      int col = n0 + wn + j * 16 + l16;
      float bv = bias[col];
      for (int t = 0; t < 4; ++t) {
        float v = acc[i][j][t] + bv;
        size_t idx = (size_t)(row + t) * N + col;
        if (EPI == 1) {
          ((float*)out)[idx] = v + res[idx];
        } else {
          ((u16*)out)[idx] = f2bf(v);
        }
      }
    }
  }
}

// ---------------- flash attention (v2: swizzled LDS + pipelined K) ----------------
// grid (S/64, B*H), block 256 (4 waves). Wave w owns q rows [q0+16w, +16).
// LDS: Kbuf[2] (16 KB each, 64x128 bf16, chunk^(row&15) swizzle)
//      Vbuf    (16 KB, 128x64 bf16, chunk^(row&7) swizzle)
//      Ps      (64 x stride-72 bf16, wave-private rows)
__global__ __launch_bounds__(256) void flash_attn(const u16* __restrict__ fused,
                                                  const u16* __restrict__ vt,
                                                  const float* __restrict__ alibi,
                                                  u16* __restrict__ ctx) {
  __shared__ __align__(16) u16 Kbuf[2][64 * 128];
  __shared__ __align__(16) u16 Vbuf[128 * 64];
  __shared__ __align__(16) u16 Ps[64 * 72];

  const int tid = threadIdx.x, wave = tid >> 6, lane = tid & 63;
  const int quad = lane >> 4, l16 = lane & 15;
  const int qt = blockIdx.x, bh = blockIdx.y;
  const int b = bh >> 5, h = bh & 31;
  const int q0 = qt * 64;
  const float scale = 0.08838834764831845f;  // 1/sqrt(128)
  const f32x4 fz = {0.f, 0.f, 0.f, 0.f};

  // --- precomputed per-lane staging sources ---
  // K/Q tile staging: inst = wave*4+j writes LDS rows [4*inst, 4*inst+4);
  // lane covers (row = 4*inst + quad, lds_chunk = l16); global chunk = l16 ^ (row&15).
  const u16* srcQ[4];
  const u16* srcK[4];  // row-relative (add kv0*12288 per tile)
  for (int j = 0; j < 4; ++j) {
    int inst = wave * 4 + j;
    int row = inst * 4 + quad;
    int cg = l16 ^ (row & 15);
    srcQ[j] = fused + (size_t)(b * 2048 + q0 + row) * 12288 + h * 384 + cg * 8;
    srcK[j] = fused + (size_t)(b * 2048 + row) * 12288 + h * 384 + 128 + cg * 8;
  }
  // V tile staging: inst writes LDS rows [8*inst, 8*inst+8) of Vbuf;
  // lane covers (row = 8*inst + (lane>>3), lds_chunk = lane&7); global chunk = lds_chunk ^ (row&7).
  const u16* srcV[4];  // add kv0 per tile
  for (int j = 0; j < 4; ++j) {
    int inst = wave * 4 + j;
    int row = inst * 8 + (lane >> 3);
    int cg = (lane & 7) ^ (row & 7);
    srcV[j] = vt + ((size_t)bh * 128 + row) * 2048 + cg * 8;
  }

  // --- prologue: stage Q into Kbuf[1], K tile 0 into Kbuf[0] ---
  for (int j = 0; j < 4; ++j) {
    int inst = wave * 4 + j;
    load16(srcQ[j], (char*)Kbuf[1] + inst * 1024);
    load16(srcK[j], (char*)Kbuf[0] + inst * 1024);
  }
  __syncthreads();  // drains vmcnt: Q + K0 resident

  // Q fragments -> registers (swizzled read, 2-way banks = free)
  bf16x8 qf[4];
  for (int kk = 0; kk < 4; ++kk) {
    int row = wave * 16 + l16;
    int cs = (kk * 4 + quad) ^ l16;
    qf[kk] = *(const bf16x8*)((const char*)Kbuf[1] + row * 256 + cs * 16);
  }
  __syncthreads();  // all waves own their Q frags before Kbuf[1] is re-staged

  float m_st[4] = {-__builtin_inff(), -__builtin_inff(), -__builtin_inff(), -__builtin_inff()};
  float l_st[4] = {0.f, 0.f, 0.f, 0.f};
  f32x4 o_acc[8];
  for (int f = 0; f < 8; ++f) o_acc[f] = fz;

  const int nkv = qt + 1;  // causal
  for (int kvt = 0; kvt < nkv; ++kvt) {
    const int kv0 = kvt * 64;
    const int cur = kvt & 1;

    // issue V(kvt) and prefetch K(kvt+1); both drain at the MID barrier,
    // hidden behind QK + softmax.
    for (int j = 0; j < 4; ++j) {
      int inst = wave * 4 + j;
      load16(srcV[j] + kv0, (char*)Vbuf + inst * 1024);
    }
    if (kvt + 1 < nkv) {
      for (int j = 0; j < 4; ++j) {
        int inst = wave * 4 + j;
        load16(srcK[j] + (size_t)(kv0 + 64) * 12288, (char*)Kbuf[cur ^ 1] + inst * 1024);
      }
    }

    // S = Q K^T : per wave 16q x 64kv (K tile was drained by last iter's mid barrier)
    f32x4 sa[4];
    for (int j = 0; j < 4; ++j) sa[j] = fz;
    for (int kk = 0; kk < 4; ++kk) {
      for (int j = 0; j < 4; ++j) {
        int row = j * 16 + l16;
        int cs = (kk * 4 + quad) ^ l16;
        bf16x8 bv = *(const bf16x8*)((const char*)Kbuf[cur] + row * 256 + cs * 16);
        sa[j] = __builtin_amdgcn_mfma_f32_16x16x32_bf16(qf[kk], bv, sa[j], 0, 0, 0);
      }
    }

    // scale + alibi + causal mask
    float al[4];
    for (int j = 0; j < 4; ++j) al[j] = alibi[(size_t)bh * 2048 + kv0 + j * 16 + l16];
    float p[4][4];
    const bool diag = (kvt == qt);
    for (int j = 0; j < 4; ++j) {
      int kvg = kv0 + j * 16 + l16;
      for (int t = 0; t < 4; ++t) {
        float v = sa[j][t] * scale + al[j];
        if (diag) {
          int qg = q0 + wave * 16 + quad * 4 + t;
          if (kvg > qg) v = -__builtin_inff();
        }
        p[j][t] = v;
      }
    }

    // online softmax (row r = quad*4+t lives in the 16 lanes sharing quad)
    float mnew[4], alpha[4];
    for (int t = 0; t < 4; ++t) {
      float mx = fmaxf(fmaxf(p[0][t], p[1][t]), fmaxf(p[2][t], p[3][t]));
      for (int off = 1; off < 16; off <<= 1) mx = fmaxf(mx, __shfl_xor(mx, off, 64));
      mnew[t] = fmaxf(m_st[t], mx);
      alpha[t] = __expf(m_st[t] - mnew[t]);
      m_st[t] = mnew[t];
      float rs = 0.f;
      for (int j = 0; j < 4; ++j) {
        p[j][t] = __expf(p[j][t] - mnew[t]);
        rs += p[j][t];
      }
      for (int off = 1; off < 16; off <<= 1) rs += __shfl_xor(rs, off, 64);
      l_st[t] = l_st[t] * alpha[t] + rs;
    }
    for (int f = 0; f < 8; ++f)
      for (int t = 0; t < 4; ++t) o_acc[f][t] *= alpha[t];

    // P: C-layout -> A-layout via LDS (wave-private rows, stride 72 => 2-way banks)
    for (int j = 0; j < 4; ++j)
      for (int t = 0; t < 4; ++t)
        Ps[(wave * 16 + quad * 4 + t) * 72 + j * 16 + l16] = f2bf(p[j][t]);

    __syncthreads();  // MID: drains V(kvt) (+K(kvt+1)) staging — hidden by QK+softmax

    // O += P V  (A from Ps, B from swizzled Vbuf)
    for (int kk = 0; kk < 2; ++kk) {
      bf16x8 a = *(const bf16x8*)((const char*)Ps + ((wave * 16 + l16) * 72 + kk * 32 + quad * 8) * 2);
      for (int f = 0; f < 8; ++f) {
        int row = f * 16 + l16;
        int cs = (kk * 4 + quad) ^ (l16 & 7);
        bf16x8 bv = *(const bf16x8*)((const char*)Vbuf + row * 128 + cs * 16);
        o_acc[f] = __builtin_amdgcn_mfma_f32_16x16x32_bf16(a, bv, o_acc[f], 0, 0, 0);
      }
    }

    __syncthreads();  // END: Vbuf readers done (cheap: no loads in flight since MID)
  }

  // epilogue: ctx[b,s,h*128+d] bf16
  float invl[4];
  for (int t = 0; t < 4; ++t) invl[t] = 1.0f / l_st[t];
  for (int f = 0; f < 8; ++f) {
    int d = h * 128 + f * 16 + l16;
    for (int t = 0; t < 4; ++t) {
      int row = b * 2048 + q0 + wave * 16 + quad * 4 + t;
      ctx[(size_t)row * 4096 + d] = f2bf(o_acc[f][t] * invl[t]);
    }
  }
}

// ---------------- launch ----------------
extern "C" void kernel_launch(void* const* d_in, const int* in_sizes, int n_in,
                              void* d_out, int out_size, void* d_ws, size_t ws_size,
                              hipStream_t stream) {
  const float* hs    = (const float*)d_in[0];
  const float* resid = (const float*)d_in[1];
  const float* alibi = (const float*)d_in[2];
  // d_in[3] = attention_mask: deterministic causal, computed analytically
  const float* Wqkv  = (const float*)d_in[4];
  const float* bqkv  = (const float*)d_in[5];
  const float* Wd    = (const float*)d_in[6];
  const float* bd    = (const float*)d_in[7];

  char* ws = (char*)d_ws;
  u16* Abf   = (u16*)(ws);                        // 32 MB
  u16* W1T   = (u16*)(ws + (size_t)33554432);     // 96 MB
  u16* fused = (u16*)(ws + (size_t)134217728);    // 96 MB
  u16* vtb   = (u16*)(ws + (size_t)234881024);    // 32 MB
  u16* ctx   = (u16*)(ws);                        // reuse Abf (dead after GEMM1)
  u16* W2T   = (u16*)(ws + (size_t)33554432);     // reuse W1T (dead after GEMM1)

  cvt_bf16<<<16384, 256, 0, stream>>>(hs, Abf, 16777216);
  cvt_transpose<<<dim3(384, 128), 256, 0, stream>>>(Wqkv, W1T, 4096, 12288);
  gemm_bt<0><<<dim3(96, 32), 256, 0, stream>>>(Abf, W1T, bqkv, nullptr, fused, 4096, 12288, 4096);
  transpose_v<<<dim3(32, 64), 256, 0, stream>>>(fused, vtb);
  cvt_transpose<<<dim3(128, 128), 256, 0, stream>>>(Wd, W2T, 4096, 4096);  // after GEMM1 read of W1T
  flash_attn<<<dim3(32, 64), 256, 0, stream>>>(fused, vtb, alibi, ctx);    // ctx overwrites Abf after GEMM1
  gemm_bt<1><<<dim3(32, 32), 256, 0, stream>>>(ctx, W2T, bd, resid, d_out, 4096, 4096, 4096);
}